// Round 9
// baseline (440.660 us; speedup 1.0000x reference)
//
#include <hip/hip_runtime.h>

typedef __attribute__((ext_vector_type(8))) short bf16x8;
typedef __attribute__((ext_vector_type(4))) float f32x4;

#define MFMA_BF16(a, b, c) __builtin_amdgcn_mfma_f32_16x16x32_bf16((a), (b), (c), 0, 0, 0)
#define VMCNT(N) asm volatile("s_waitcnt vmcnt(" #N ")" ::: "memory")
#define BAR() asm volatile("s_barrier" ::: "memory")

__device__ __forceinline__ unsigned short bf16rn(float f) {
  unsigned u = __builtin_bit_cast(unsigned, f);
  u += 0x7fffu + ((u >> 16) & 1u);
  return (unsigned short)(u >> 16);
}

__device__ __forceinline__ void gld_lds16(const void* g, void* l) {
  __builtin_amdgcn_global_load_lds((const __attribute__((address_space(1))) void*)g,
                                   (__attribute__((address_space(3))) void*)l, 16, 0, 0);
}

// ---------------- weight convert + transpose: W[K][N] f32 -> W^T[N][K] bf16 ----------------
__global__ __launch_bounds__(256) void convT_kernel(
    const float* __restrict__ wq, const float* __restrict__ wk,
    const float* __restrict__ wv, const float* __restrict__ wo,
    const float* __restrict__ wfc, const float* __restrict__ wpj,
    unsigned short* __restrict__ wsb)
{
  const int bid = blockIdx.x;
  const float* src; unsigned short* dst; int K, N, lb;
  if (bid < 1024) {
    const int m = bid >> 8; lb = bid & 255; K = 1024; N = 1024;
    src = (m == 0) ? wq : (m == 1) ? wk : (m == 2) ? wv : wo;
    dst = wsb + (size_t)m * 1048576u;
  } else if (bid < 2048) {
    lb = bid - 1024; K = 1024; N = 4096; src = wfc; dst = wsb + 4194304u;
  } else {
    lb = bid - 2048; K = 4096; N = 1024; src = wpj; dst = wsb + 8388608u;
  }
  const int tiles_k = K >> 6;
  const int tk = lb % tiles_k, tn = lb / tiles_k;
  const int k0 = tk << 6, n0 = tn << 6;
  const int t = threadIdx.x, kq = t & 15, nq = t >> 4;
  float4 r[4];
#pragma unroll
  for (int i = 0; i < 4; ++i)
    r[i] = *(const float4*)(src + (size_t)(k0 + kq * 4 + i) * N + n0 + nq * 4);
#pragma unroll
  for (int j = 0; j < 4; ++j) {
    ushort4 o;
    o.x = bf16rn(((const float*)&r[0])[j]);
    o.y = bf16rn(((const float*)&r[1])[j]);
    o.z = bf16rn(((const float*)&r[2])[j]);
    o.w = bf16rn(((const float*)&r[3])[j]);
    *(ushort4*)(dst + (size_t)(n0 + nq * 4 + j) * K + k0 + kq * 4) = o;
  }
}

// ---------------- layernorm: f32 [rows][1024] -> bf16 ----------------
__global__ __launch_bounds__(256) void ln_kernel(
    const float* __restrict__ x, const float* __restrict__ sc,
    const float* __restrict__ sh, unsigned short* __restrict__ out)
{
  const int row = blockIdx.x, t = threadIdx.x;
  const float4 v = *(const float4*)(x + (size_t)row * 1024 + t * 4);
  float s = v.x + v.y + v.z + v.w;
  float q = v.x * v.x + v.y * v.y + v.z * v.z + v.w * v.w;
#pragma unroll
  for (int off = 1; off < 64; off <<= 1) { s += __shfl_xor(s, off); q += __shfl_xor(q, off); }
  __shared__ float ps[4], pq[4];
  if ((t & 63) == 0) { ps[t >> 6] = s; pq[t >> 6] = q; }
  __syncthreads();
  s = ps[0] + ps[1] + ps[2] + ps[3];
  q = pq[0] + pq[1] + pq[2] + pq[3];
  const float mean = s * (1.f / 1024.f);
  const float var = q * (1.f / 1024.f) - mean * mean;
  const float inv = rsqrtf(var + 1e-5f);
  const float4 scv = *(const float4*)(sc + t * 4);
  const float4 shv = *(const float4*)(sh + t * 4);
  ushort4 o;
  o.x = bf16rn((v.x - mean) * inv * scv.x + shv.x);
  o.y = bf16rn((v.y - mean) * inv * scv.y + shv.y);
  o.z = bf16rn((v.z - mean) * inv * scv.z + shv.z);
  o.w = bf16rn((v.w - mean) * inv * scv.w + shv.w);
  *(ushort4*)(out + (size_t)row * 1024 + t * 4) = o;
}

// ---------------- old 128x128 GEMM, kept only for EPI=1 (V with transposed store) ---------
template<int EPI>
__global__ __launch_bounds__(256) void gemm_bt(
    const unsigned short* __restrict__ A, const unsigned short* __restrict__ Bt,
    int M, int N, int K,
    unsigned short* __restrict__ outb, float* __restrict__ outf,
    const float* __restrict__ bias, const float* __restrict__ resid)
{
  __shared__ char smem[36864];
  const int t = threadIdx.x;
  const int lane = t & 63, w = t >> 6;
  const int g = lane >> 4, l15 = lane & 15;
  const int wr = w >> 1, wc = w & 1;
  const int m0 = blockIdx.x * 128, n0 = blockIdx.y * 128;

  f32x4 acc[4][4] = {};

  const int nkt = K >> 5;
  for (int kt = 0; kt < nkt; ++kt) {
    const int k0 = kt << 5;
    __syncthreads();
#pragma unroll
    for (int it = 0; it < 2; ++it) {
      const int c = it * 256 + t;
      const int row = c >> 2;
      const int ce = (c & 3) << 3;
      gld_lds16(A + (size_t)(m0 + row) * K + k0 + ce,
                smem + ((it * 256 + w * 64) << 4));
      gld_lds16(Bt + (size_t)(n0 + row) * K + k0 + ce,
                smem + 8192 + ((it * 256 + w * 64) << 4));
    }
    __syncthreads();
    bf16x8 a[4], b[4];
#pragma unroll
    for (int mi = 0; mi < 4; ++mi)
      a[mi] = *(const bf16x8*)(smem + (wr * 64 + mi * 16 + l15) * 64 + g * 16);
#pragma unroll
    for (int ni = 0; ni < 4; ++ni)
      b[ni] = *(const bf16x8*)(smem + 8192 + (wc * 64 + ni * 16 + l15) * 64 + g * 16);
#pragma unroll
    for (int mi = 0; mi < 4; ++mi)
#pragma unroll
      for (int ni = 0; ni < 4; ++ni)
        acc[mi][ni] = MFMA_BF16(a[mi], b[ni], acc[mi][ni]);
  }

  if constexpr (EPI == 1) {  // transposed store for V
    __syncthreads();
    unsigned short* T = (unsigned short*)(smem + w * 9216);  // [64 n][72 m-padded]
#pragma unroll
    for (int mi = 0; mi < 4; ++mi)
#pragma unroll
      for (int ni = 0; ni < 4; ++ni)
#pragma unroll
        for (int r = 0; r < 4; ++r)
          T[(ni * 16 + l15) * 72 + mi * 16 + 4 * g + r] = bf16rn(acc[mi][ni][r]);
    asm volatile("s_waitcnt lgkmcnt(0)" ::: "memory");
    const int bidx = m0 >> 11;
    const int srow = (m0 & 2047) + wr * 64 + ((lane & 7) << 3);
#pragma unroll
    for (int rr = 0; rr < 8; ++rr) {
      const int trow = rr * 8 + (lane >> 3);
      bf16x8 v = *(const bf16x8*)((char*)T + trow * 144 + ((lane & 7) << 4));
      *(bf16x8*)(outb + (size_t)(bidx * 1024 + n0 + wc * 64 + trow) * 2048 + srow) = v;
    }
  }
}

// ---------------- 256x256 BK=64 4-quadrant-phase GEMM (m201-style, re-derived) -----------
// LDS per dbuf: A [256 rows][64 k] at 0 (32KB), B same at 32768. dbuf stride 65536.
// Swizzle involution: 16B-slot' = slot ^ (row&7), applied on stage SOURCE and on reads.
// Staging: row-coalesced (8 lanes/row, permuted within the row's 128B -> full lines).
// Phases per K-tile (quadrant order (qm,qn) = 00,10,11,01; frags register-reused):
//   p0: read A(qm0) 8 + B(qn0) 4 | stage A02(kt+1) | V4 | bar | 16 MFMA | bar
//   p1: read A(qm1) 8           | stage B0 (kt+1)  | V4 | bar | 16 MFMA | bar
//   p2: read B(qn1) 4           | stage A13(kt+1)  |    | bar | 16 MFMA | bar
//   p3: (all frags held)        | stage B1 (kt+1)  | V4 | bar | 16 MFMA | bar
// vmcnt ledger (2 ops/phase): every gate proves ops issued >=2 phases earlier; never 0
// mid-loop. Tail (no stage): V2 at p0, V0 at p1 (ops then 4 phases old -> no stall).
// EPI 0: bf16 store; 2: f32 = acc + bias + resid; 3: bf16 = gelu(acc + bias)
template<int EPI>
__global__ __launch_bounds__(512, 2) void g256(
    const unsigned short* __restrict__ A, const unsigned short* __restrict__ Bt,
    int M, int N, int K, int stripeLg,
    unsigned short* __restrict__ outb, float* __restrict__ outf,
    const float* __restrict__ bias, const float* __restrict__ resid)
{
  extern __shared__ char smem[];
  const int t = threadIdx.x, lane = t & 63, w = t >> 6;
  const int g = lane >> 4, l15 = lane & 15;
  const int wr = w >> 2, wc = w & 3;  // 2M x 4N waves; wave tile 128 x 64
  const int bid = blockIdx.x;
  const int tm = ((bid & 7) << stripeLg) + ((bid >> 3) & ((1 << stripeLg) - 1));
  const int tn = bid >> (3 + stripeLg);
  const int m0 = tm << 8, n0 = tn << 8;

  // ---- staging geometry: lane covers (row = base + (lane>>3), slot = lane&7) ----
  const int arl = lane >> 3;                    // row-within-8
  const int colswz = ((lane & 7) ^ arl) << 3;   // source k-element offset (slot^row&7)*8
  // A quarters q: rows q*64 + w*8 + arl
  const unsigned short* pa0 = A + (size_t)(m0 + 0 * 64 + w * 8 + arl) * K + colswz;
  const unsigned short* pa1 = A + (size_t)(m0 + 1 * 64 + w * 8 + arl) * K + colswz;
  const unsigned short* pa2 = A + (size_t)(m0 + 2 * 64 + w * 8 + arl) * K + colswz;
  const unsigned short* pa3 = A + (size_t)(m0 + 3 * 64 + w * 8 + arl) * K + colswz;
  const int da0 = (0 * 64 + w * 8) * 128, da1 = (1 * 64 + w * 8) * 128;
  const int da2 = (2 * 64 + w * 8) * 128, da3 = (3 * 64 + w * 8) * 128;
  // B halves hn (rows with bit5==hn): rows (w&3)*64 + hn*32 + (w>>2)*16 + o*8 + arl
  const int brbase = (w & 3) * 64 + (w >> 2) * 16;
  const unsigned short* pb00 = Bt + (size_t)(n0 + brbase + 0 + 0 + arl) * K + colswz;
  const unsigned short* pb01 = Bt + (size_t)(n0 + brbase + 0 + 8 + arl) * K + colswz;
  const unsigned short* pb10 = Bt + (size_t)(n0 + brbase + 32 + 0 + arl) * K + colswz;
  const unsigned short* pb11 = Bt + (size_t)(n0 + brbase + 32 + 8 + arl) * K + colswz;
  const int db00 = 32768 + (brbase + 0) * 128, db01 = 32768 + (brbase + 8) * 128;
  const int db10 = 32768 + (brbase + 32) * 128, db11 = 32768 + (brbase + 40) * 128;

  // ---- read swizzle (lane-constant): slot' = (kk*4+g) ^ (l15&7) ----
  const int sw0 = (((0 * 4 + g) ^ (l15 & 7)) << 4);
  const int sw1 = (((1 * 4 + g) ^ (l15 & 7)) << 4);

  f32x4 acc[8][4] = {};
  const int NT = K >> 6;

#define LDA(CB, QM, AV) { _Pragma("unroll") for (int mi = 0; mi < 4; ++mi) {              \
    const int row_ = (wr * 128 + (QM) * 64 + mi * 16 + l15) * 128;                        \
    AV[mi][0] = *(const bf16x8*)((CB) + row_ + sw0);                                      \
    AV[mi][1] = *(const bf16x8*)((CB) + row_ + sw1); } }
#define LDB(CB, QN, BV) { _Pragma("unroll") for (int ni = 0; ni < 2; ++ni) {              \
    const int row_ = 32768 + (wc * 64 + (QN) * 32 + ni * 16 + l15) * 128;                 \
    BV[ni][0] = *(const bf16x8*)((CB) + row_ + sw0);                                      \
    BV[ni][1] = *(const bf16x8*)((CB) + row_ + sw1); } }
#define MMQ(AV, BV, QM, QN) { __builtin_amdgcn_s_setprio(1);                              \
    _Pragma("unroll") for (int mi = 0; mi < 4; ++mi)                                      \
      _Pragma("unroll") for (int ni = 0; ni < 2; ++ni) {                                  \
        acc[(QM)*4+mi][(QN)*2+ni] = MFMA_BF16(AV[mi][0], BV[ni][0], acc[(QM)*4+mi][(QN)*2+ni]); \
        acc[(QM)*4+mi][(QN)*2+ni] = MFMA_BF16(AV[mi][1], BV[ni][1], acc[(QM)*4+mi][(QN)*2+ni]); } \
    __builtin_amdgcn_s_setprio(0); }

  bf16x8 aq0[4][2], aq1[4][2], bq0[2][2], bq1[2][2];

  // prologue: stage K-tile 0 into dbuf0, order [A02, B0, A13, B1]; prove A02+B0
  gld_lds16(pa0, smem + da0); gld_lds16(pa2, smem + da2);
  gld_lds16(pb00, smem + db00); gld_lds16(pb01, smem + db01);
  gld_lds16(pa1, smem + da1); gld_lds16(pa3, smem + da3);
  gld_lds16(pb10, smem + db10); gld_lds16(pb11, smem + db11);
  VMCNT(4);
  BAR();

  for (int kt = 0; kt < NT; ++kt) {
    char* cb = smem + (kt & 1) * 65536;
    char* nb = smem + ((kt & 1) ^ 1) * 65536;
    const bool st = (kt + 1) < NT;
    const int kn = (kt + 1) * 64;
    // ---- p0: quadrant (0,0) ----
    LDA(cb, 0, aq0);
    LDB(cb, 0, bq0);
    if (st) { gld_lds16(pa0 + kn, nb + da0); gld_lds16(pa2 + kn, nb + da2); }
    if (st) VMCNT(4); else VMCNT(2);
    BAR();
    MMQ(aq0, bq0, 0, 0);
    BAR();
    // ---- p1: quadrant (1,0) ----
    LDA(cb, 1, aq1);
    if (st) { gld_lds16(pb00 + kn, nb + db00); gld_lds16(pb01 + kn, nb + db01); }
    if (st) VMCNT(4); else VMCNT(0);
    BAR();
    MMQ(aq1, bq0, 1, 0);
    BAR();
    // ---- p2: quadrant (1,1) ----
    LDB(cb, 1, bq1);
    if (st) { gld_lds16(pa1 + kn, nb + da1); gld_lds16(pa3 + kn, nb + da3); }
    BAR();
    MMQ(aq1, bq1, 1, 1);
    BAR();
    // ---- p3: quadrant (0,1), all frags held ----
    if (st) { gld_lds16(pb10 + kn, nb + db10); gld_lds16(pb11 + kn, nb + db11); }
    if (st) VMCNT(4);
    BAR();
    MMQ(aq0, bq1, 0, 1);
    BAR();
  }
#undef LDA
#undef LDB
#undef MMQ

  // epilogue; acc[ai][ci]: row = (ai>>2)*64 + (ai&3)*16 + g*4 + r; col = (ci>>1)*32 + (ci&1)*16 + l15
  if constexpr (EPI == 2) {
#pragma unroll
    for (int ai = 0; ai < 8; ++ai) {
      const int ro = ((ai >> 2) << 6) + ((ai & 3) << 4) + g * 4;
#pragma unroll
      for (int ci = 0; ci < 4; ++ci) {
        const int n = n0 + wc * 64 + ((ci >> 1) << 5) + ((ci & 1) << 4) + l15;
        const float bn = bias[n];
#pragma unroll
        for (int r = 0; r < 4; ++r) {
          const size_t m = m0 + wr * 128 + ro + r;
          outf[m * N + n] = acc[ai][ci][r] + bn + resid[m * N + n];
        }
      }
    }
  } else {
    __syncthreads();  // all K-loop LDS traffic done before bounce overwrites buffers
    char* wsl = smem + w * 16384;  // per-wave bounce [128 rows][64 cols] bf16
#pragma unroll
    for (int ai = 0; ai < 8; ++ai) {
      const int ro = ((ai >> 2) << 6) + ((ai & 3) << 4) + g * 4;
#pragma unroll
      for (int ci = 0; ci < 4; ++ci) {
        const int co = ((ci >> 1) << 5) + ((ci & 1) << 4) + l15;
        float bn = 0.f;
        if constexpr (EPI == 3) bn = bias[n0 + wc * 64 + co];
#pragma unroll
        for (int r = 0; r < 4; ++r) {
          float v = acc[ai][ci][r];
          if constexpr (EPI == 3) {
            v += bn;
            const float inner = 0.7978845608028654f * (v + 0.044715f * v * v * v);
            v = 0.5f * v * (1.0f + tanhf(inner));
          }
          *(unsigned short*)(wsl + (ro + r) * 128 + co * 2) = bf16rn(v);
        }
      }
    }
    // same-wave LDS RAW ordered by compiler lgkmcnt
#pragma unroll
    for (int s = 0; s < 16; ++s) {
      const int row = s * 8 + (lane >> 3);
      bf16x8 vv = *(const bf16x8*)(wsl + row * 128 + (lane & 7) * 16);
      *(bf16x8*)(outb + (size_t)(m0 + wr * 128 + row) * N + n0 + wc * 64 + (lane & 7) * 8) = vv;
    }
  }
}

// ---------------- flash attention, causal, D=64, QB=128 (4 waves x 32 rows), KB=64 --------
// Q/K come from the fused QK buffer [8192][2048]: Q at cols 0-1023, K at cols 1024-2047.
__global__ __launch_bounds__(256) void attn_kernel(
    const unsigned short* __restrict__ qg, const unsigned short* __restrict__ kg,
    const unsigned short* __restrict__ vT, unsigned short* __restrict__ ctx)
{
  __shared__ char smem[34816];  // K 8KB | V_T 8KB | P 4x4608
  const int bh = blockIdx.x, b = bh >> 4, h = bh & 15;
  const int t = threadIdx.x, lane = t & 63, w = t >> 6, g = lane >> 4, l15 = lane & 15;
  char* Ks = smem;
  char* Vs = smem + 8192;
  char* Ps = smem + 16384 + w * 4608;

  const float SC = 0.18033688011112042f;  // 0.125 * log2(e)

  for (int pass = 0; pass < 2; ++pass) {
    const int qt = pass ? 15 - (int)blockIdx.y : (int)blockIdx.y;
    const int q0 = qt << 7;
    const int q0w = q0 + w * 32;

    bf16x8 qf[2][2];
#pragma unroll
    for (int mi = 0; mi < 2; ++mi)
#pragma unroll
      for (int ks = 0; ks < 2; ++ks)
        qf[mi][ks] = *(const bf16x8*)(qg + (size_t)(b * 2048 + q0w + mi * 16 + l15) * 2048 +
                                      h * 64 + ks * 32 + g * 8);

    f32x4 acc[2][4] = {};
    float lsum[2][4] = {};

    const int ntile = 2 * qt + 2;
    for (int kt = 0; kt < ntile; ++kt) {
      const int kv0 = kt << 6;
      __syncthreads();
#pragma unroll
      for (int it = 0; it < 2; ++it) {
        const int c = it * 256 + t;
        const int row = c >> 3;
        const int wb = (c & 7) << 4;
        const int sw = (wb ^ ((row & 7) << 4)) >> 1;
        gld_lds16(kg + (size_t)(b * 2048 + kv0 + row) * 2048 + h * 64 + sw,
                  Ks + ((it * 256 + w * 64) << 4));
        gld_lds16(vT + (size_t)(b * 1024 + h * 64 + row) * 2048 + kv0 + sw,
                  Vs + ((it * 256 + w * 64) << 4));
      }
      __syncthreads();

      f32x4 sf[2][4] = {};
#pragma unroll
      for (int nb = 0; nb < 4; ++nb) {
        const int krow = nb * 16 + l15;
#pragma unroll
        for (int ks = 0; ks < 2; ++ks) {
          bf16x8 kf = *(const bf16x8*)(Ks + krow * 128 +
                                       (((ks * 32 + g * 8) << 1) ^ ((krow & 7) << 4)));
          sf[0][nb] = MFMA_BF16(qf[0][ks], kf, sf[0][nb]);
          sf[1][nb] = MFMA_BF16(qf[1][ks], kf, sf[1][nb]);
        }
      }
      if (kv0 + 63 > q0w) {
#pragma unroll
        for (int mi = 0; mi < 2; ++mi)
#pragma unroll
          for (int nb = 0; nb < 4; ++nb)
#pragma unroll
            for (int r = 0; r < 4; ++r) {
              const int qq = q0w + mi * 16 + 4 * g + r;
              const int kk = kv0 + nb * 16 + l15;
              if (kk > qq) sf[mi][nb][r] = -__builtin_inff();
            }
      }
#pragma unroll
      for (int mi = 0; mi < 2; ++mi)
#pragma unroll
        for (int nb = 0; nb < 4; ++nb)
#pragma unroll
          for (int r = 0; r < 4; ++r) {
            const float p = exp2f(__builtin_fmaf(sf[mi][nb][r], SC, -4.0f));
            sf[mi][nb][r] = p;
            lsum[mi][r] += p;
          }
#pragma unroll
      for (int mi = 0; mi < 2; ++mi)
#pragma unroll
        for (int nb = 0; nb < 4; ++nb)
#pragma unroll
          for (int r = 0; r < 4; ++r)
            *(unsigned short*)(Ps + (mi * 16 + 4 * g + r) * 144 + ((nb * 16 + l15) << 1)) =
                bf16rn(sf[mi][nb][r]);
      asm volatile("s_waitcnt lgkmcnt(0)" ::: "memory");
#pragma unroll
      for (int mi = 0; mi < 2; ++mi)
#pragma unroll
        for (int ks = 0; ks < 2; ++ks) {
          bf16x8 pa = *(const bf16x8*)(Ps + (mi * 16 + l15) * 144 + ((ks * 32 + g * 8) << 1));
#pragma unroll
          for (int nb = 0; nb < 4; ++nb) {
            const int drow = nb * 16 + l15;
            bf16x8 vb = *(const bf16x8*)(Vs + drow * 128 +
                                         (((ks * 32 + g * 8) << 1) ^ ((drow & 7) << 4)));
            acc[mi][nb] = MFMA_BF16(pa, vb, acc[mi][nb]);
          }
        }
    }
#pragma unroll
    for (int mi = 0; mi < 2; ++mi)
#pragma unroll
      for (int r = 0; r < 4; ++r) {
        float s = lsum[mi][r];
        s += __shfl_xor(s, 1);
        s += __shfl_xor(s, 2);
        s += __shfl_xor(s, 4);
        s += __shfl_xor(s, 8);
        lsum[mi][r] = s;
      }
#pragma unroll
    for (int mi = 0; mi < 2; ++mi) {
      float inv[4];
#pragma unroll
      for (int r = 0; r < 4; ++r) inv[r] = 1.0f / lsum[mi][r];
#pragma unroll
      for (int nb = 0; nb < 4; ++nb)
#pragma unroll
        for (int r = 0; r < 4; ++r)
          ctx[(size_t)(b * 2048 + q0w + mi * 16 + 4 * g + r) * 1024 + h * 64 + nb * 16 + l15] =
              bf16rn(acc[mi][nb][r] * inv[r]);
    }
  }
}

extern "C" void kernel_launch(void* const* d_in, const int* in_sizes, int n_in,
                              void* d_out, int out_size, void* d_ws, size_t ws_size,
                              hipStream_t stream)
{
  const float* x   = (const float*)d_in[0];
  const float* l1s = (const float*)d_in[1];
  const float* l1b = (const float*)d_in[2];
  const float* l2s = (const float*)d_in[3];
  const float* l2b = (const float*)d_in[4];
  const float* Wq  = (const float*)d_in[5];
  const float* Wk  = (const float*)d_in[6];
  const float* Wv  = (const float*)d_in[7];
  const float* Wo  = (const float*)d_in[8];
  const float* bo  = (const float*)d_in[9];
  const float* Wfc = (const float*)d_in[10];
  const float* bfc = (const float*)d_in[11];
  const float* Wpj = (const float*)d_in[12];
  const float* bpj = (const float*)d_in[13];
  float* out = (float*)d_out;
  char* ws = (char*)d_ws;

  // workspace layout (bytes)
  unsigned short* wT   = (unsigned short*)ws;                // 24MB: [wqT wkT][wvT][woT][wfcT][wpjT]
  unsigned short* wqkT = wT;                                 // [2048][1024] fused Q|K
  unsigned short* wvT  = wT + 2097152u;
  unsigned short* woT  = wT + 3145728u;
  unsigned short* wfcT = wT + 4194304u;
  unsigned short* wpjT = wT + 8388608u;
  unsigned short* ln1x = (unsigned short*)(ws + 25165824u);  // 16MB
  unsigned short* qkb  = (unsigned short*)(ws + 41943040u);  // 32MB [8192][2048] fused Q|K out
  unsigned short* vTb  = (unsigned short*)(ws + 75497472u);  // 16MB [b*1024+h*64+d][2048]
  unsigned short* ctx  = (unsigned short*)(ws + 92274688u);  // 16MB (reused as ln2x)
  unsigned short* ln2x = ctx;
  float* hbuf          = (float*)(ws + 109051904u);          // 32MB
  unsigned short* fcb  = (unsigned short*)(ws + 25165824u);  // 64MB, reuses ln1x..vTb region

  convT_kernel<<<3072, 256, 0, stream>>>(Wq, Wk, Wv, Wo, Wfc, Wpj, wT);
  ln_kernel<<<8192, 256, 0, stream>>>(x, l1s, l1b, ln1x);
  // fused Q+K GEMM: [8192][1024] x [2048][1024]^T -> [8192][2048]
  g256<0><<<256, 512, 131072, stream>>>(ln1x, wqkT, 8192, 2048, 1024, 2,
                                        qkb, nullptr, nullptr, nullptr);
  gemm_bt<1><<<dim3(64, 8), 256, 0, stream>>>(ln1x, wvT, 8192, 1024, 1024,
                                              vTb, nullptr, nullptr, nullptr);
  attn_kernel<<<dim3(64, 8), 256, 0, stream>>>(qkb, qkb + 1024, vTb, ctx);
  g256<2><<<128, 512, 131072, stream>>>(ctx, woT, 8192, 1024, 1024, 2,
                                        nullptr, hbuf, bo, x);
  ln_kernel<<<8192, 256, 0, stream>>>(hbuf, l2s, l2b, ln2x);
  g256<3><<<512, 512, 131072, stream>>>(ln2x, wfcT, 8192, 4096, 1024, 2,
                                        fcb, nullptr, bfc, nullptr);
  g256<2><<<128, 512, 131072, stream>>>(fcb, wpjT, 8192, 1024, 4096, 2,
                                        nullptr, out, bpj, hbuf);
}